// Round 1
// baseline (71.395 us; speedup 1.0000x reference)
//
#include <hip/hip_runtime.h>
#include <hip/hip_bf16.h>

// Leapfrog KDK integrator, softened point-mass accel:
//   a(q) = -GM * q / (r*(r+A)^2 + 1e-12),  GM = A = 1
// Reference semantics:
//   t_f = ts[N-1] + 0.001 ; dt_i = (t_f - ts[i]) / n_steps
//   64 steps of: p_half = p + 0.5*dt*a(q); q += dt*p_half; p = p_half + 0.5*dt*a(q)
// Output rows (2N x 6): row 2i = trail[i], row 2i+1 = lead[i].
//
// Bitwise-safe optimization: accel(q_new) of step k == accel(q) of step k+1,
// so evaluate accel once per step (65 total instead of 128).

#define N_PART 65536

__device__ __forceinline__ void accel(float qx, float qy, float qz,
                                      float& ax, float& ay, float& az) {
    float r2 = qx * qx + qy * qy + qz * qz;
    float r  = sqrtf(r2);
    float rp = r + 1.0f;                 // r + A_SCALE
    float denom = r * rp * rp + 1e-12f;  // r*(r+A)^2 + eps
    float inv = -1.0f / denom;           // fold GM=1 and the minus sign
    ax = qx * inv;
    ay = qy * inv;
    az = qz * inv;
}

__global__ void __launch_bounds__(256)
leapfrog_kernel(const float* __restrict__ ts,
                const float* __restrict__ w0_lead,
                const float* __restrict__ w0_trail,
                const int* __restrict__ n_steps_p,
                float* __restrict__ out) {
    const int tid = blockIdx.x * blockDim.x + threadIdx.x;
    if (tid >= 2 * N_PART) return;

    const int i       = tid >> 1;
    const int is_lead = tid & 1;   // row 2i -> trail, row 2i+1 -> lead

    const float* __restrict__ src = is_lead ? w0_lead : w0_trail;

    const float t_f = ts[N_PART - 1] + 0.001f;
    const int n_steps = *n_steps_p;
    const float dt  = (t_f - ts[i]) / (float)n_steps;
    const float hdt = 0.5f * dt;

    const long base = (long)i * 6;
    float qx = src[base + 0];
    float qy = src[base + 1];
    float qz = src[base + 2];
    float px = src[base + 3];
    float py = src[base + 4];
    float pz = src[base + 5];

    float ax, ay, az;
    accel(qx, qy, qz, ax, ay, az);

    for (int s = 0; s < n_steps; ++s) {
        // kick (half)
        const float phx = px + hdt * ax;
        const float phy = py + hdt * ay;
        const float phz = pz + hdt * az;
        // drift
        qx += dt * phx;
        qy += dt * phy;
        qz += dt * phz;
        // accel at new position (reused as next step's opening accel)
        accel(qx, qy, qz, ax, ay, az);
        // kick (half)
        px = phx + hdt * ax;
        py = phy + hdt * ay;
        pz = phz + hdt * az;
    }

    const long obase = (long)tid * 6;
    out[obase + 0] = qx;
    out[obase + 1] = qy;
    out[obase + 2] = qz;
    out[obase + 3] = px;
    out[obase + 4] = py;
    out[obase + 5] = pz;
}

extern "C" void kernel_launch(void* const* d_in, const int* in_sizes, int n_in,
                              void* d_out, int out_size, void* d_ws, size_t ws_size,
                              hipStream_t stream) {
    const float* ts       = (const float*)d_in[0];
    const float* w0_lead  = (const float*)d_in[1];
    const float* w0_trail = (const float*)d_in[2];
    const int*   n_steps  = (const int*)d_in[3];
    float* out = (float*)d_out;

    const int total = 2 * N_PART;                 // 131072 threads
    const int block = 256;
    const int grid  = (total + block - 1) / block; // 512 blocks

    leapfrog_kernel<<<grid, block, 0, stream>>>(ts, w0_lead, w0_trail, n_steps, out);
}

// Round 2
// 63.869 us; speedup vs baseline: 1.1178x; 1.1178x over previous
//
#include <hip/hip_runtime.h>
#include <hip/hip_bf16.h>

// Leapfrog KDK integrator, softened point-mass accel:
//   a(q) = -q / (r*(r+1)^2 + 1e-12)
// Reference: t_f = ts[N-1]+0.001; dt_i = (t_f - ts[i])/n_steps; 64 KDK steps.
// Output rows (2N x 6): row 2i = trail[i], row 2i+1 = lead[i].
//
// Optimizations vs R1 (all numerically ~1-ulp-level perturbations, chaos-
// amplified to absmax << 0.25 threshold):
//  - v_sqrt_f32 / v_rcp_f32 approx intrinsics instead of precise IEEE
//    sequences (the div fixup chain dominated the serial latency).
//  - Kick folding: trailing half-kick of step s + leading half-kick of
//    step s+1 share the same accel and same dt -> one full kick. Half
//    kicks only at the two boundaries.
//  - a = q*(-inv), kick += dt*a  ->  c = -dt*inv; ph = fma(c, q, ph).

#define N_PART 65536

// Returns -1 / (r*(r+1)^2 + 1e-12) for position q.
__device__ __forceinline__ float neg_inv_denom(float qx, float qy, float qz) {
    float r2 = fmaf(qx, qx, fmaf(qy, qy, qz * qz));
    float r  = __builtin_amdgcn_sqrtf(r2);      // v_sqrt_f32, ~1 ulp, 0 -> 0
    float rp = r + 1.0f;
    float d  = fmaf(r * rp, rp, 1e-12f);
    return -__builtin_amdgcn_rcpf(d);           // v_rcp_f32, ~1 ulp
}

__global__ void __launch_bounds__(256)
leapfrog_kernel(const float* __restrict__ ts,
                const float* __restrict__ w0_lead,
                const float* __restrict__ w0_trail,
                const int* __restrict__ n_steps_p,
                float* __restrict__ out) {
    const int tid = blockIdx.x * blockDim.x + threadIdx.x;
    if (tid >= 2 * N_PART) return;

    const int i       = tid >> 1;
    const int is_lead = tid & 1;   // row 2i -> trail, row 2i+1 -> lead

    const float* __restrict__ src = is_lead ? w0_lead : w0_trail;

    const float t_f     = ts[N_PART - 1] + 0.001f;
    const int   n_steps = *n_steps_p;
    const float dt      = (t_f - ts[i]) / (float)n_steps;
    const float hdt     = 0.5f * dt;

    const long base = (long)i * 6;
    float qx = src[base + 0];
    float qy = src[base + 1];
    float qz = src[base + 2];
    float px = src[base + 3];
    float py = src[base + 4];
    float pz = src[base + 5];

    // Opening half kick: ph = p + hdt * a(q0)
    float c  = hdt * neg_inv_denom(qx, qy, qz);
    float phx = fmaf(c, qx, px);
    float phy = fmaf(c, qy, py);
    float phz = fmaf(c, qz, pz);

    // n_steps-1 full drift+kick pairs (folded half-kicks)
    #pragma unroll 4
    for (int s = 0; s < n_steps - 1; ++s) {
        qx = fmaf(dt, phx, qx);
        qy = fmaf(dt, phy, qy);
        qz = fmaf(dt, phz, qz);
        c  = dt * neg_inv_denom(qx, qy, qz);
        phx = fmaf(c, qx, phx);
        phy = fmaf(c, qy, phy);
        phz = fmaf(c, qz, phz);
    }

    // Final drift + closing half kick
    qx = fmaf(dt, phx, qx);
    qy = fmaf(dt, phy, qy);
    qz = fmaf(dt, phz, qz);
    c  = hdt * neg_inv_denom(qx, qy, qz);
    px = fmaf(c, qx, phx);
    py = fmaf(c, qy, phy);
    pz = fmaf(c, qz, phz);

    const long obase = (long)tid * 6;
    out[obase + 0] = qx;
    out[obase + 1] = qy;
    out[obase + 2] = qz;
    out[obase + 3] = px;
    out[obase + 4] = py;
    out[obase + 5] = pz;
}

extern "C" void kernel_launch(void* const* d_in, const int* in_sizes, int n_in,
                              void* d_out, int out_size, void* d_ws, size_t ws_size,
                              hipStream_t stream) {
    const float* ts       = (const float*)d_in[0];
    const float* w0_lead  = (const float*)d_in[1];
    const float* w0_trail = (const float*)d_in[2];
    const int*   n_steps  = (const int*)d_in[3];
    float* out = (float*)d_out;

    const int total = 2 * N_PART;                  // 131072 threads
    const int block = 256;
    const int grid  = (total + block - 1) / block; // 512 blocks

    leapfrog_kernel<<<grid, block, 0, stream>>>(ts, w0_lead, w0_trail, n_steps, out);
}